// Round 1
// baseline (2254.818 us; speedup 1.0000x reference)
//
#include <hip/hip_runtime.h>
#include <hip/hip_bf16.h>
#include <cstdint>
#include <cstddef>

#define D_MODEL 768
#define D_INNER 1536
#define DT_RANK 48
#define D_STATE 16
#define SEQ     1024
#define BATCH   2
#define NROWS   2048      // BATCH*SEQ
#define VOCAB   32000

typedef __hip_bfloat16 bf16;
typedef short bf16x8 __attribute__((ext_vector_type(8)));   // 8 bf16 in 4 VGPRs
typedef float f32x4  __attribute__((ext_vector_type(4)));

// ---------------------------------------------------------------------------
// async global->LDS, 16B per lane. LDS dest = wave-uniform base + lane*16.
__device__ __forceinline__ void async_copy16(void* lds, const void* gp) {
    __builtin_amdgcn_global_load_lds(
        (const __attribute__((address_space(1))) unsigned int*)gp,
        (__attribute__((address_space(3)))       unsigned int*)lds,
        16, 0, 0);
}

// ---------------------------------------------------------------------------
// GEMM: C(M,N) = A(M,K) * B(N,K)^T.  A,B bf16 row-major (K contiguous), C f32.
// M % 128 == 0, K % 32 == 0, N arbitrary (B row index clamped, store guarded).
// EPI: 0 = store, 1 = C += v (residual add), 2 = C = softplus(v + bias[col]).
template<int EPI>
__global__ __launch_bounds__(256) void gemm_bt(
    const bf16* __restrict__ A, const bf16* __restrict__ B,
    float* __restrict__ C, const float* __restrict__ bias,
    int M, int N, int K, int ntm)
{
    __shared__ bf16 sA[128 * 32];
    __shared__ bf16 sB[128 * 32];
    const int bid  = blockIdx.x;
    const int m0   = (bid % ntm) * 128;
    const int n0   = (bid / ntm) * 128;
    const int t    = threadIdx.x;
    const int wave = t >> 6;
    const int lane = t & 63;
    // staging: each wave fills a contiguous 1KB LDS chunk; lane l -> +l*16B
    const int r0 = wave * 16 + (lane >> 2);      // tile row 0..63
    const int c0 = (lane & 3) * 8;               // k element offset 0/8/16/24
    // fragment indices
    const int wm = (wave & 1) * 64;
    const int wn = (wave >> 1) * 64;
    const int fm = lane & 15;
    const int kq = (lane >> 4) * 8;

    f32x4 acc[4][4];
    #pragma unroll
    for (int i = 0; i < 4; ++i)
        #pragma unroll
        for (int j = 0; j < 4; ++j)
            acc[i][j] = {0.f, 0.f, 0.f, 0.f};

    int nr0 = n0 + r0;      if (nr0 > N - 1) nr0 = N - 1;
    int nr1 = n0 + 64 + r0; if (nr1 > N - 1) nr1 = N - 1;

    const bf16* gA0 = A + (size_t)(m0 + r0)      * K + c0;
    const bf16* gA1 = A + (size_t)(m0 + 64 + r0) * K + c0;
    const bf16* gB0 = B + (size_t)nr0 * K + c0;
    const bf16* gB1 = B + (size_t)nr1 * K + c0;
    char* lA0 = (char*)sA + wave * 1024;
    char* lA1 = (char*)sA + 4096 + wave * 1024;
    char* lB0 = (char*)sB + wave * 1024;
    char* lB1 = (char*)sB + 4096 + wave * 1024;

    for (int k0 = 0; k0 < K; k0 += 32) {
        async_copy16(lA0, gA0 + k0);
        async_copy16(lA1, gA1 + k0);
        async_copy16(lB0, gB0 + k0);
        async_copy16(lB1, gB1 + k0);
        __syncthreads();   // drains vmcnt before barrier (compiler-enforced)

        bf16x8 af[4], bfr[4];
        #pragma unroll
        for (int i = 0; i < 4; ++i) {
            af[i]  = *(const bf16x8*)&sA[(wm + i * 16 + fm) * 32 + kq];
            bfr[i] = *(const bf16x8*)&sB[(wn + i * 16 + fm) * 32 + kq];
        }
        #pragma unroll
        for (int i = 0; i < 4; ++i)
            #pragma unroll
            for (int j = 0; j < 4; ++j)
                acc[i][j] = __builtin_amdgcn_mfma_f32_16x16x32_bf16(
                    af[i], bfr[j], acc[i][j], 0, 0, 0);
        __syncthreads();
    }

    // C/D layout: col = lane&15, row = (lane>>4)*4 + reg
    const int lr = (lane >> 4) * 4;
    const int lc = lane & 15;
    #pragma unroll
    for (int i = 0; i < 4; ++i) {
        #pragma unroll
        for (int j = 0; j < 4; ++j) {
            const int col = n0 + wn + j * 16 + lc;
            if (col >= N) continue;
            #pragma unroll
            for (int r = 0; r < 4; ++r) {
                const int row = m0 + wm + i * 16 + lr + r;
                const size_t o = (size_t)row * N + col;
                float v = acc[i][j][r];
                if (EPI == 1) {
                    C[o] += v;
                } else if (EPI == 2) {
                    v += bias[col];
                    v = (v > 15.f) ? v : __logf(1.f + __expf(v));
                    C[o] = v;
                } else {
                    C[o] = v;
                }
            }
        }
    }
}

// ---------------------------------------------------------------------------
__global__ __launch_bounds__(192) void embed_kernel(
    const int* __restrict__ ids, const float* __restrict__ emb,
    float* __restrict__ x)
{
    const int row = blockIdx.x;
    const int t = threadIdx.x;                       // 192 threads * float4 = 768
    const float4* src = (const float4*)(emb + (size_t)ids[row] * D_MODEL);
    float4* dst = (float4*)(x + (size_t)row * D_MODEL);
    dst[t] = src[t];
}

// ---------------------------------------------------------------------------
__global__ __launch_bounds__(256) void rmsnorm_kernel(
    const float* __restrict__ x, const float* __restrict__ w,
    bf16* __restrict__ out)
{
    const int row = blockIdx.x;
    const float* xr = x + (size_t)row * D_MODEL;
    const int t = threadIdx.x;
    float v0 = xr[t], v1 = xr[t + 256], v2 = xr[t + 512];
    float s = v0 * v0 + v1 * v1 + v2 * v2;
    #pragma unroll
    for (int m = 1; m < 64; m <<= 1) s += __shfl_xor(s, m);
    __shared__ float red[4];
    if ((t & 63) == 0) red[t >> 6] = s;
    __syncthreads();
    s = red[0] + red[1] + red[2] + red[3];
    const float sc = rsqrtf(s * (1.f / 768.f) + 1e-5f);
    bf16* o = out + (size_t)row * D_MODEL;
    o[t]       = __float2bfloat16(v0 * sc * w[t]);
    o[t + 256] = __float2bfloat16(v1 * sc * w[t + 256]);
    o[t + 512] = __float2bfloat16(v2 * sc * w[t + 512]);
}

// ---------------------------------------------------------------------------
__global__ __launch_bounds__(256) void cvt_bf16_kernel(
    const float* __restrict__ src, bf16* __restrict__ dst, int n)
{
    const int i = blockIdx.x * 256 + threadIdx.x;
    if (i < n) dst[i] = __float2bfloat16(src[i]);
}

// all four per-layer weight buffers in one launch (dt_proj K-padded 48->64)
__global__ __launch_bounds__(256) void cvt_layer_weights(
    const float* __restrict__ ipw, const float* __restrict__ xpw,
    const float* __restrict__ dtw, const float* __restrict__ opw,
    bf16* __restrict__ wip, bf16* __restrict__ wxp,
    bf16* __restrict__ wdt, bf16* __restrict__ wop)
{
    int i = blockIdx.x * 256 + threadIdx.x;
    if (i < 3072 * 768) { wip[i] = __float2bfloat16(ipw[i]); return; }
    i -= 3072 * 768;
    if (i < 80 * 1536)  { wxp[i] = __float2bfloat16(xpw[i]); return; }
    i -= 80 * 1536;
    if (i < 1536 * 64) {
        const int r = i >> 6, c = i & 63;
        wdt[i] = __float2bfloat16(c < DT_RANK ? dtw[r * DT_RANK + c] : 0.f);
        return;
    }
    i -= 1536 * 64;
    if (i < 768 * 1536) { wop[i] = __float2bfloat16(opw[i]); }
}

// delta_raw = x_dbl[:, 0:48], zero-padded to K=64, bf16
__global__ __launch_bounds__(256) void pad_dt_kernel(
    const float* __restrict__ x_dbl, bf16* __restrict__ out)
{
    const int i = blockIdx.x * 256 + threadIdx.x;   // 2048*64
    const int r = i >> 6, c = i & 63;
    out[i] = __float2bfloat16(c < DT_RANK ? x_dbl[r * 80 + c] : 0.f);
}

// ---------------------------------------------------------------------------
// causal depthwise conv (k=4) + bias + silu; writes f32 (for scan) + bf16 (GEMM A)
__global__ __launch_bounds__(256) void conv_silu_kernel(
    const float* __restrict__ xr, const float* __restrict__ cw,
    const float* __restrict__ cb, float* __restrict__ uf,
    bf16* __restrict__ ub)
{
    const int idx = blockIdx.x * 256 + threadIdx.x;   // < 2048*1536
    const int di  = idx % D_INNER;
    const int row = idx / D_INNER;
    const int l   = row & (SEQ - 1);
    float acc = cb[di];
    #pragma unroll
    for (int j = 0; j < 4; ++j) {
        const int ll = l - 3 + j;
        if (ll >= 0)
            acc += cw[di * 4 + j] * xr[(size_t)(row - 3 + j) * 3072 + di];
    }
    const float s = acc / (1.f + __expf(-acc));
    uf[idx] = s;
    ub[idx] = __float2bfloat16(s);
}

// ---------------------------------------------------------------------------
// selective scan: lane = (channel-group g = tid/16, state n = tid%16).
// 16 channels per block, 192 blocks. Fuses +u*D and *silu(res), writes y bf16.
__global__ __launch_bounds__(256) void scan_kernel(
    const float* __restrict__ delta,   // 2048 x 1536
    const float* __restrict__ u,       // 2048 x 1536
    const float* __restrict__ x_dbl,   // 2048 x 80 (B at +48, C at +64)
    const float* __restrict__ xr,      // 2048 x 3072 (res at +1536)
    const float* __restrict__ A_log,   // 1536 x 16
    const float* __restrict__ Dp,      // 1536
    bf16* __restrict__ yb)             // 2048 x 1536
{
    const int n  = threadIdx.x & 15;
    const int g  = threadIdx.x >> 4;
    const int ch = blockIdx.x * 16 + g;      // 0..3071
    const int b  = ch / D_INNER;
    const int di = ch % D_INNER;

    const float An = -__expf(A_log[di * D_STATE + n]);
    const float Dv = Dp[di];
    float h = 0.f;

    const float* drow = delta + (size_t)b * SEQ * D_INNER + di;
    const float* urow = u     + (size_t)b * SEQ * D_INNER + di;
    const float* rrow = xr    + (size_t)b * SEQ * 3072 + D_INNER + di;
    const float* xdr  = x_dbl + (size_t)b * SEQ * 80;
    bf16* yrow        = yb    + (size_t)b * SEQ * D_INNER + di;

    #pragma unroll 4
    for (int t = 0; t < SEQ; ++t) {
        const float dv = drow[(size_t)t * D_INNER];
        const float uv = urow[(size_t)t * D_INNER];
        const float Bv = xdr[t * 80 + 48 + n];
        const float Cv = xdr[t * 80 + 64 + n];
        const float dA = __expf(dv * An);
        h = dA * h + (dv * Bv) * uv;           // only loop-carried dep
        float p = h * Cv;
        p += __shfl_xor(p, 1);
        p += __shfl_xor(p, 2);
        p += __shfl_xor(p, 4);
        p += __shfl_xor(p, 8);
        if (n == 0) {
            float y = p + uv * Dv;
            const float r = rrow[(size_t)t * 3072];
            y *= r / (1.f + __expf(-r));       // * silu(res)
            yrow[(size_t)t * D_INNER] = __float2bfloat16(y);
        }
    }
}

// ---------------------------------------------------------------------------
extern "C" void kernel_launch(void* const* d_in, const int* in_sizes, int n_in,
                              void* d_out, int out_size, void* d_ws, size_t ws_size,
                              hipStream_t stream)
{
    const int*   ids    = (const int*)  d_in[0];
    const float* emb    = (const float*)d_in[1];
    const float* norm_w = (const float*)d_in[2];
    const float* ipw    = (const float*)d_in[3];
    const float* cw     = (const float*)d_in[4];
    const float* cb     = (const float*)d_in[5];
    const float* xpw    = (const float*)d_in[6];
    const float* dtw    = (const float*)d_in[7];
    const float* dtb    = (const float*)d_in[8];
    const float* alog   = (const float*)d_in[9];
    const float* Dp     = (const float*)d_in[10];
    const float* opw    = (const float*)d_in[11];
    const float* nfw    = (const float*)d_in[12];
    float* out = (float*)d_out;

    // -------- workspace layout (~79.6 MB) --------
    char* ws = (char*)d_ws;
    bf16*  emb_bf = (bf16*)ws;  ws += (size_t)VOCAB * D_MODEL * 2;   // 49,152,000
    float* x      = (float*)ws; ws += (size_t)NROWS * D_MODEL * 4;   //  6,291,456
    bf16*  xn     = (bf16*)ws;  ws += (size_t)NROWS * D_MODEL * 2;   //  3,145,728
    bf16*  ub     = (bf16*)ws;  ws += (size_t)NROWS * D_INNER * 2;   //  6,291,456
    float* xdbl   = (float*)ws; ws += (size_t)NROWS * 80 * 4;        //    655,360
    bf16*  dtraw  = (bf16*)ws;  ws += (size_t)NROWS * 64 * 2;        //    262,144
    bf16*  yb     = (bf16*)ws;  ws += (size_t)NROWS * D_INNER * 2;   //  6,291,456
    bf16*  wip    = (bf16*)ws;  ws += (size_t)3072 * 768 * 2;        //  4,718,592
    bf16*  wxp    = (bf16*)ws;  ws += (size_t)80 * 1536 * 2;         //    245,760
    bf16*  wdt    = (bf16*)ws;  ws += (size_t)1536 * 64 * 2;         //    196,608
    bf16*  wop    = (bf16*)ws;  ws += (size_t)768 * 1536 * 2;        //  2,359,296

    // -------- big transients live in d_out (262 MB), overwritten by logits --------
    char* ob = (char*)d_out;
    float* xr    = (float*)ob;  ob += (size_t)NROWS * 3072 * 4;      // 25,165,824
    float* uf    = (float*)ob;  ob += (size_t)NROWS * D_INNER * 4;   // 12,582,912
    float* delta = (float*)ob;  ob += (size_t)NROWS * D_INNER * 4;   // 12,582,912

    cvt_bf16_kernel<<<(VOCAB * D_MODEL + 255) / 256, 256, 0, stream>>>(
        emb, emb_bf, VOCAB * D_MODEL);
    embed_kernel<<<NROWS, 192, 0, stream>>>(ids, emb, x);

    for (int l = 0; l < 2; ++l) {
        cvt_layer_weights<<<(3760128 + 255) / 256, 256, 0, stream>>>(
            ipw + (size_t)l * 3072 * 768, xpw + (size_t)l * 80 * 1536,
            dtw + (size_t)l * 1536 * DT_RANK, opw + (size_t)l * 768 * 1536,
            wip, wxp, wdt, wop);
        rmsnorm_kernel<<<NROWS, 256, 0, stream>>>(x, norm_w + l * D_MODEL, xn);
        // in_proj: (2048x768)(3072x768)^T -> xr
        gemm_bt<0><<<16 * 24, 256, 0, stream>>>(xn, wip, xr, nullptr,
                                                NROWS, 3072, D_MODEL, 16);
        conv_silu_kernel<<<NROWS * D_INNER / 256, 256, 0, stream>>>(
            xr, cw + (size_t)l * D_INNER * 4, cb + (size_t)l * D_INNER, uf, ub);
        // x_proj: (2048x1536)(80x1536)^T -> x_dbl
        gemm_bt<0><<<16 * 1, 256, 0, stream>>>(ub, wxp, xdbl, nullptr,
                                               NROWS, 80, D_INNER, 16);
        pad_dt_kernel<<<NROWS * 64 / 256, 256, 0, stream>>>(xdbl, dtraw);
        // dt_proj + softplus: (2048x64)(1536x64)^T -> delta
        gemm_bt<2><<<16 * 12, 256, 0, stream>>>(dtraw, wdt, delta,
                                                dtb + (size_t)l * D_INNER,
                                                NROWS, D_INNER, 64, 16);
        scan_kernel<<<192, 256, 0, stream>>>(delta, uf, xdbl, xr,
                                             alog + (size_t)l * D_INNER * D_STATE,
                                             Dp + (size_t)l * D_INNER, yb);
        // out_proj with residual add into x
        gemm_bt<1><<<16 * 6, 256, 0, stream>>>(yb, wop, x, nullptr,
                                               NROWS, D_MODEL, D_INNER, 16);
    }

    rmsnorm_kernel<<<NROWS, 256, 0, stream>>>(x, nfw, xn);
    // logits: (2048x768)(32000x768)^T -> out
    gemm_bt<0><<<16 * 250, 256, 0, stream>>>(xn, emb_bf, out, nullptr,
                                             NROWS, VOCAB, D_MODEL, 16);
}

// Round 2
// 1054.168 us; speedup vs baseline: 2.1390x; 2.1390x over previous
//
#include <hip/hip_runtime.h>
#include <hip/hip_bf16.h>
#include <cstdint>
#include <cstddef>

#define D_MODEL 768
#define D_INNER 1536
#define DT_RANK 48
#define D_STATE 16
#define SEQ     1024
#define BATCH   2
#define NROWS   2048      // BATCH*SEQ
#define VOCAB   32000
#define LCHUNK  16
#define NCHUNK  64        // SEQ / LCHUNK
#define CHST    49152     // 3072 channels * 16 states

typedef __hip_bfloat16 bf16;
typedef short bf16x8 __attribute__((ext_vector_type(8)));   // 8 bf16 in 4 VGPRs
typedef float f32x4  __attribute__((ext_vector_type(4)));
struct bf8 { bf16 v[8]; };

// ---------------------------------------------------------------------------
// async global->LDS, 16B per lane. LDS dest = wave-uniform base + lane*16.
__device__ __forceinline__ void async_copy16(void* lds, const void* gp) {
    __builtin_amdgcn_global_load_lds(
        (const __attribute__((address_space(1))) unsigned int*)gp,
        (__attribute__((address_space(3)))       unsigned int*)lds,
        16, 0, 0);
}

// ---------------------------------------------------------------------------
// GEMM: C(M,N) = A(M,K) * B(N,K)^T.  A,B bf16 row-major (K contiguous), C f32.
// M % 128 == 0, K % 32 == 0, N arbitrary (B row index clamped, store guarded).
// EPI: 0 = store, 1 = C += v (residual add), 2 = C = softplus(v + bias[col]).
template<int EPI>
__global__ __launch_bounds__(256) void gemm_bt(
    const bf16* __restrict__ A, const bf16* __restrict__ B,
    float* __restrict__ C, const float* __restrict__ bias,
    int M, int N, int K, int ntm)
{
    __shared__ bf16 sA[128 * 32];
    __shared__ bf16 sB[128 * 32];
    const int bid  = blockIdx.x;
    const int m0   = (bid % ntm) * 128;
    const int n0   = (bid / ntm) * 128;
    const int t    = threadIdx.x;
    const int wave = t >> 6;
    const int lane = t & 63;
    // staging: each wave fills a contiguous 1KB LDS chunk; lane l -> +l*16B
    const int r0 = wave * 16 + (lane >> 2);      // tile row 0..63
    const int c0 = (lane & 3) * 8;               // k element offset 0/8/16/24
    // fragment indices
    const int wm = (wave & 1) * 64;
    const int wn = (wave >> 1) * 64;
    const int fm = lane & 15;
    const int kq = (lane >> 4) * 8;

    f32x4 acc[4][4];
    #pragma unroll
    for (int i = 0; i < 4; ++i)
        #pragma unroll
        for (int j = 0; j < 4; ++j)
            acc[i][j] = {0.f, 0.f, 0.f, 0.f};

    int nr0 = n0 + r0;      if (nr0 > N - 1) nr0 = N - 1;
    int nr1 = n0 + 64 + r0; if (nr1 > N - 1) nr1 = N - 1;

    const bf16* gA0 = A + (size_t)(m0 + r0)      * K + c0;
    const bf16* gA1 = A + (size_t)(m0 + 64 + r0) * K + c0;
    const bf16* gB0 = B + (size_t)nr0 * K + c0;
    const bf16* gB1 = B + (size_t)nr1 * K + c0;
    char* lA0 = (char*)sA + wave * 1024;
    char* lA1 = (char*)sA + 4096 + wave * 1024;
    char* lB0 = (char*)sB + wave * 1024;
    char* lB1 = (char*)sB + 4096 + wave * 1024;

    for (int k0 = 0; k0 < K; k0 += 32) {
        async_copy16(lA0, gA0 + k0);
        async_copy16(lA1, gA1 + k0);
        async_copy16(lB0, gB0 + k0);
        async_copy16(lB1, gB1 + k0);
        __syncthreads();

        bf16x8 af[4], bfr[4];
        #pragma unroll
        for (int i = 0; i < 4; ++i) {
            af[i]  = *(const bf16x8*)&sA[(wm + i * 16 + fm) * 32 + kq];
            bfr[i] = *(const bf16x8*)&sB[(wn + i * 16 + fm) * 32 + kq];
        }
        #pragma unroll
        for (int i = 0; i < 4; ++i)
            #pragma unroll
            for (int j = 0; j < 4; ++j)
                acc[i][j] = __builtin_amdgcn_mfma_f32_16x16x32_bf16(
                    af[i], bfr[j], acc[i][j], 0, 0, 0);
        __syncthreads();
    }

    // C/D layout: col = lane&15, row = (lane>>4)*4 + reg
    const int lr = (lane >> 4) * 4;
    const int lc = lane & 15;
    #pragma unroll
    for (int i = 0; i < 4; ++i) {
        #pragma unroll
        for (int j = 0; j < 4; ++j) {
            const int col = n0 + wn + j * 16 + lc;
            if (col >= N) continue;
            #pragma unroll
            for (int r = 0; r < 4; ++r) {
                const int row = m0 + wm + i * 16 + lr + r;
                const size_t o = (size_t)row * N + col;
                float v = acc[i][j][r];
                if (EPI == 1) {
                    C[o] += v;
                } else if (EPI == 2) {
                    v += bias[col];
                    v = (v > 15.f) ? v : __logf(1.f + __expf(v));
                    C[o] = v;
                } else {
                    C[o] = v;
                }
            }
        }
    }
}

// ---------------------------------------------------------------------------
__global__ __launch_bounds__(192) void embed_kernel(
    const int* __restrict__ ids, const float* __restrict__ emb,
    float* __restrict__ x)
{
    const int row = blockIdx.x;
    const int t = threadIdx.x;                       // 192 threads * float4 = 768
    const float4* src = (const float4*)(emb + (size_t)ids[row] * D_MODEL);
    float4* dst = (float4*)(x + (size_t)row * D_MODEL);
    dst[t] = src[t];
}

// ---------------------------------------------------------------------------
__global__ __launch_bounds__(256) void rmsnorm_kernel(
    const float* __restrict__ x, const float* __restrict__ w,
    bf16* __restrict__ out)
{
    const int row = blockIdx.x;
    const float* xr = x + (size_t)row * D_MODEL;
    const int t = threadIdx.x;
    float v0 = xr[t], v1 = xr[t + 256], v2 = xr[t + 512];
    float s = v0 * v0 + v1 * v1 + v2 * v2;
    #pragma unroll
    for (int m = 1; m < 64; m <<= 1) s += __shfl_xor(s, m);
    __shared__ float red[4];
    if ((t & 63) == 0) red[t >> 6] = s;
    __syncthreads();
    s = red[0] + red[1] + red[2] + red[3];
    const float sc = rsqrtf(s * (1.f / 768.f) + 1e-5f);
    bf16* o = out + (size_t)row * D_MODEL;
    o[t]       = __float2bfloat16(v0 * sc * w[t]);
    o[t + 256] = __float2bfloat16(v1 * sc * w[t + 256]);
    o[t + 512] = __float2bfloat16(v2 * sc * w[t + 512]);
}

// ---------------------------------------------------------------------------
// vectorized f32 -> bf16, 8 elements per thread (n % 8 == 0)
__global__ __launch_bounds__(256) void cvt_bf16_kernel(
    const float* __restrict__ src, bf16* __restrict__ dst, int n)
{
    const int i = (blockIdx.x * 256 + threadIdx.x) * 8;
    if (i >= n) return;
    const float4 a = *(const float4*)(src + i);
    const float4 b = *(const float4*)(src + i + 4);
    bf8 o;
    o.v[0] = __float2bfloat16(a.x); o.v[1] = __float2bfloat16(a.y);
    o.v[2] = __float2bfloat16(a.z); o.v[3] = __float2bfloat16(a.w);
    o.v[4] = __float2bfloat16(b.x); o.v[5] = __float2bfloat16(b.y);
    o.v[6] = __float2bfloat16(b.z); o.v[7] = __float2bfloat16(b.w);
    *(bf8*)(dst + i) = o;
}

// all four per-layer weight buffers in one launch (dt_proj K-padded 48->64)
__global__ __launch_bounds__(256) void cvt_layer_weights(
    const float* __restrict__ ipw, const float* __restrict__ xpw,
    const float* __restrict__ dtw, const float* __restrict__ opw,
    bf16* __restrict__ wip, bf16* __restrict__ wxp,
    bf16* __restrict__ wdt, bf16* __restrict__ wop)
{
    int i = blockIdx.x * 256 + threadIdx.x;
    if (i < 3072 * 768) { wip[i] = __float2bfloat16(ipw[i]); return; }
    i -= 3072 * 768;
    if (i < 80 * 1536)  { wxp[i] = __float2bfloat16(xpw[i]); return; }
    i -= 80 * 1536;
    if (i < 1536 * 64) {
        const int r = i >> 6, c = i & 63;
        wdt[i] = __float2bfloat16(c < DT_RANK ? dtw[r * DT_RANK + c] : 0.f);
        return;
    }
    i -= 1536 * 64;
    if (i < 768 * 1536) { wop[i] = __float2bfloat16(opw[i]); }
}

// delta_raw = x_dbl[:, 0:48], zero-padded to K=64, bf16
__global__ __launch_bounds__(256) void pad_dt_kernel(
    const float* __restrict__ x_dbl, bf16* __restrict__ out)
{
    const int i = blockIdx.x * 256 + threadIdx.x;   // 2048*64
    const int r = i >> 6, c = i & 63;
    out[i] = __float2bfloat16(c < DT_RANK ? x_dbl[r * 80 + c] : 0.f);
}

// ---------------------------------------------------------------------------
// causal depthwise conv (k=4) + bias + silu; writes f32 (for scan) + bf16 (GEMM A)
__global__ __launch_bounds__(256) void conv_silu_kernel(
    const float* __restrict__ xr, const float* __restrict__ cw,
    const float* __restrict__ cb, float* __restrict__ uf,
    bf16* __restrict__ ub)
{
    const int idx = blockIdx.x * 256 + threadIdx.x;   // < 2048*1536
    const int di  = idx % D_INNER;
    const int row = idx / D_INNER;
    const int l   = row & (SEQ - 1);
    float acc = cb[di];
    #pragma unroll
    for (int j = 0; j < 4; ++j) {
        const int ll = l - 3 + j;
        if (ll >= 0)
            acc += cw[di * 4 + j] * xr[(size_t)(row - 3 + j) * 3072 + di];
    }
    const float s = acc / (1.f + __expf(-acc));
    uf[idx] = s;
    ub[idx] = __float2bfloat16(s);
}

// ---------------------------------------------------------------------------
// Chunked selective scan. Recurrence h[t] = a[t] h[t-1] + b[t] split into
// NCHUNK chunks of LCHUNK steps.  Layout of P/H/Hin: [chunk][ch*16 + n]
// (coalesced in both the per-chunk and the combine kernels).
//
// Pass 1: per (ch, chunk): P = prod a[t], H = local end state (zero init).
__global__ __launch_bounds__(256) void scan_pass1(
    const float* __restrict__ delta, const float* __restrict__ u,
    const float* __restrict__ x_dbl, const float* __restrict__ A_log,
    float* __restrict__ P, float* __restrict__ H)
{
    const int n  = threadIdx.x & 15;
    const int g  = threadIdx.x >> 4;
    const int ch = blockIdx.x * 16 + g;      // 0..3071
    const int k  = blockIdx.y;               // chunk
    const int b  = ch / D_INNER;
    const int di = ch % D_INNER;
    const int t0 = k * LCHUNK;

    const float An = -__expf(A_log[di * D_STATE + n]);
    const float* drow = delta + ((size_t)b * SEQ + t0) * D_INNER + di;
    const float* urow = u     + ((size_t)b * SEQ + t0) * D_INNER + di;
    const float* xdr  = x_dbl + ((size_t)b * SEQ + t0) * 80;

    float h = 0.f, ap = 1.f;
    #pragma unroll
    for (int t = 0; t < LCHUNK; ++t) {
        const float dv = drow[t * D_INNER];
        const float uv = urow[t * D_INNER];
        const float Bv = xdr[t * 80 + 48 + n];
        const float a  = __expf(dv * An);
        h = a * h + (dv * Bv) * uv;
        ap *= a;
    }
    const size_t o = (size_t)k * CHST + ch * 16 + n;
    P[o] = ap;
    H[o] = h;
}

// Pass 2: serial combine across chunks; emits each chunk's initial state.
__global__ __launch_bounds__(256) void scan_pass2(
    const float* __restrict__ P, const float* __restrict__ H,
    float* __restrict__ Hin)
{
    const int id = blockIdx.x * 256 + threadIdx.x;   // < CHST
    float h = 0.f;
    #pragma unroll 16
    for (int k = 0; k < NCHUNK; ++k) {
        const size_t o = (size_t)k * CHST + id;
        Hin[o] = h;
        h = P[o] * h + H[o];
    }
}

// Pass 3: re-scan each chunk from Hin; C-dot via shfl reduce; epilogue fused.
__global__ __launch_bounds__(256) void scan_pass3(
    const float* __restrict__ delta, const float* __restrict__ u,
    const float* __restrict__ x_dbl, const float* __restrict__ xr,
    const float* __restrict__ A_log, const float* __restrict__ Dp,
    const float* __restrict__ Hin, bf16* __restrict__ yb)
{
    const int n  = threadIdx.x & 15;
    const int g  = threadIdx.x >> 4;
    const int ch = blockIdx.x * 16 + g;
    const int k  = blockIdx.y;
    const int b  = ch / D_INNER;
    const int di = ch % D_INNER;
    const int t0 = k * LCHUNK;

    const float An = -__expf(A_log[di * D_STATE + n]);
    const float Dv = Dp[di];
    const float* drow = delta + ((size_t)b * SEQ + t0) * D_INNER + di;
    const float* urow = u     + ((size_t)b * SEQ + t0) * D_INNER + di;
    const float* rrow = xr + ((size_t)b * SEQ + t0) * 3072 + D_INNER + di;
    const float* xdr  = x_dbl + ((size_t)b * SEQ + t0) * 80;
    bf16* yrow = yb + ((size_t)b * SEQ + t0) * D_INNER + di;

    float h = Hin[(size_t)k * CHST + ch * 16 + n];
    #pragma unroll
    for (int t = 0; t < LCHUNK; ++t) {
        const float dv = drow[t * D_INNER];
        const float uv = urow[t * D_INNER];
        const float Bv = xdr[t * 80 + 48 + n];
        const float Cv = xdr[t * 80 + 64 + n];
        const float a  = __expf(dv * An);
        h = a * h + (dv * Bv) * uv;
        float p = h * Cv;
        p += __shfl_xor(p, 1);
        p += __shfl_xor(p, 2);
        p += __shfl_xor(p, 4);
        p += __shfl_xor(p, 8);
        if (n == 0) {
            float y = p + uv * Dv;
            const float r = rrow[t * 3072];
            y *= r / (1.f + __expf(-r));       // * silu(res)
            yrow[t * D_INNER] = __float2bfloat16(y);
        }
    }
}

// ---------------------------------------------------------------------------
extern "C" void kernel_launch(void* const* d_in, const int* in_sizes, int n_in,
                              void* d_out, int out_size, void* d_ws, size_t ws_size,
                              hipStream_t stream)
{
    const int*   ids    = (const int*)  d_in[0];
    const float* emb    = (const float*)d_in[1];
    const float* norm_w = (const float*)d_in[2];
    const float* ipw    = (const float*)d_in[3];
    const float* cw     = (const float*)d_in[4];
    const float* cb     = (const float*)d_in[5];
    const float* xpw    = (const float*)d_in[6];
    const float* dtw    = (const float*)d_in[7];
    const float* dtb    = (const float*)d_in[8];
    const float* alog   = (const float*)d_in[9];
    const float* Dp     = (const float*)d_in[10];
    const float* opw    = (const float*)d_in[11];
    const float* nfw    = (const float*)d_in[12];
    float* out = (float*)d_out;

    // -------- workspace layout (~79.6 MB) --------
    char* ws = (char*)d_ws;
    bf16*  emb_bf = (bf16*)ws;  ws += (size_t)VOCAB * D_MODEL * 2;
    float* x      = (float*)ws; ws += (size_t)NROWS * D_MODEL * 4;
    bf16*  xn     = (bf16*)ws;  ws += (size_t)NROWS * D_MODEL * 2;
    bf16*  ub     = (bf16*)ws;  ws += (size_t)NROWS * D_INNER * 2;
    float* xdbl   = (float*)ws; ws += (size_t)NROWS * 80 * 4;
    bf16*  dtraw  = (bf16*)ws;  ws += (size_t)NROWS * 64 * 2;
    bf16*  yb     = (bf16*)ws;  ws += (size_t)NROWS * D_INNER * 2;
    bf16*  wip    = (bf16*)ws;  ws += (size_t)3072 * 768 * 2;
    bf16*  wxp    = (bf16*)ws;  ws += (size_t)80 * 1536 * 2;
    bf16*  wdt    = (bf16*)ws;  ws += (size_t)1536 * 64 * 2;
    bf16*  wop    = (bf16*)ws;  ws += (size_t)768 * 1536 * 2;

    // -------- big transients live in d_out (262 MB), overwritten by logits --------
    char* ob = (char*)d_out;
    float* xr    = (float*)ob;  ob += (size_t)NROWS * 3072 * 4;      // 25.2 MB
    float* uf    = (float*)ob;  ob += (size_t)NROWS * D_INNER * 4;   // 12.6 MB
    float* delta = (float*)ob;  ob += (size_t)NROWS * D_INNER * 4;   // 12.6 MB
    float* Pbuf  = (float*)ob;  ob += (size_t)NCHUNK * CHST * 4;     // 12.6 MB
    float* Hbuf  = (float*)ob;  ob += (size_t)NCHUNK * CHST * 4;     // 12.6 MB
    float* Hin   = (float*)ob;  ob += (size_t)NCHUNK * CHST * 4;     // 12.6 MB

    cvt_bf16_kernel<<<VOCAB * D_MODEL / 8 / 256, 256, 0, stream>>>(
        emb, emb_bf, VOCAB * D_MODEL);
    embed_kernel<<<NROWS, 192, 0, stream>>>(ids, emb, x);

    for (int l = 0; l < 2; ++l) {
        cvt_layer_weights<<<(3760128 + 255) / 256, 256, 0, stream>>>(
            ipw + (size_t)l * 3072 * 768, xpw + (size_t)l * 80 * 1536,
            dtw + (size_t)l * 1536 * DT_RANK, opw + (size_t)l * 768 * 1536,
            wip, wxp, wdt, wop);
        rmsnorm_kernel<<<NROWS, 256, 0, stream>>>(x, norm_w + l * D_MODEL, xn);
        // in_proj: (2048x768)(3072x768)^T -> xr
        gemm_bt<0><<<16 * 24, 256, 0, stream>>>(xn, wip, xr, nullptr,
                                                NROWS, 3072, D_MODEL, 16);
        conv_silu_kernel<<<NROWS * D_INNER / 256, 256, 0, stream>>>(
            xr, cw + (size_t)l * D_INNER * 4, cb + (size_t)l * D_INNER, uf, ub);
        // x_proj: (2048x1536)(80x1536)^T -> x_dbl
        gemm_bt<0><<<16 * 1, 256, 0, stream>>>(ub, wxp, xdbl, nullptr,
                                               NROWS, 80, D_INNER, 16);
        pad_dt_kernel<<<NROWS * 64 / 256, 256, 0, stream>>>(xdbl, dtraw);
        // dt_proj + softplus: (2048x64)(1536x64)^T -> delta
        gemm_bt<2><<<16 * 12, 256, 0, stream>>>(dtraw, wdt, delta,
                                                dtb + (size_t)l * D_INNER,
                                                NROWS, D_INNER, 64, 16);
        // chunked selective scan
        scan_pass1<<<dim3(192, NCHUNK), 256, 0, stream>>>(
            delta, uf, xdbl, alog + (size_t)l * D_INNER * D_STATE, Pbuf, Hbuf);
        scan_pass2<<<CHST / 256, 256, 0, stream>>>(Pbuf, Hbuf, Hin);
        scan_pass3<<<dim3(192, NCHUNK), 256, 0, stream>>>(
            delta, uf, xdbl, xr, alog + (size_t)l * D_INNER * D_STATE,
            Dp + (size_t)l * D_INNER, Hin, yb);
        // out_proj with residual add into x
        gemm_bt<1><<<16 * 6, 256, 0, stream>>>(yb, wop, x, nullptr,
                                               NROWS, D_MODEL, D_INNER, 16);
    }

    rmsnorm_kernel<<<NROWS, 256, 0, stream>>>(x, nfw, xn);
    // logits: (2048x768)(32000x768)^T -> out
    gemm_bt<0><<<16 * 250, 256, 0, stream>>>(xn, emb_bf, out, nullptr,
                                             NROWS, VOCAB, D_MODEL, 16);
}